// Round 3
// baseline (694.367 us; speedup 1.0000x reference)
//
#include <hip/hip_runtime.h>
#include <stdint.h>

#define K_ 8
#define N_ 512
#define NE_ 256
#define MA_ 3
#define IN_ 128
#define B_ 1024
#define STATE_ 2560
#define UNFOLDS_ 6
#define DT_ (0.04f / 6.0f)

#define BT 8        // batch columns per block
#define SROW 12     // padded LDS row stride (floats) — 48B, 16B-aligned for b128

__device__ __forceinline__ float b2f(uint16_t u) {
    union { uint32_t i; float f; } v; v.i = ((uint32_t)u) << 16; return v.f;
}
__device__ __forceinline__ uint16_t f2b(float f) {
    union { float f; uint32_t i; } v; v.f = f;
    uint32_t i = v.i;
    uint32_t r = i + 0x7FFFu + ((i >> 16) & 1u);   // RTNE
    return (uint16_t)(r >> 16);
}
__device__ __forceinline__ uint32_t pack2(uint16_t lo, uint16_t hi) {
    return (uint32_t)lo | ((uint32_t)hi << 16);
}
// dtype-adaptive load: f32!=0 -> buffer is float32, else bf16
__device__ __forceinline__ float loadf(const void* p, size_t i, int f32) {
    return f32 ? ((const float*)p)[i] : b2f(((const uint16_t*)p)[i]);
}
__device__ __forceinline__ float spf(float x) {   // softplus, stable
    return (x > 20.f) ? x : log1pf(expf(x));
}
__device__ __forceinline__ float psig(float x) {
    // S_a=0.9, S_c=0: x1=-0.55 x2=-0.45 x3=0.45 x4=0.55, k=5
    float t1 = x + 0.55f;
    float q1 = 5.f * t1 * t1;
    float t2 = x - 0.55f;
    float q2 = 1.f - 5.f * t2 * t2;
    float out = (x < -0.55f) ? 0.f : q1;
    out = (x >= -0.45f) ? (x + 0.5f) : out;
    out = (x > 0.45f) ? q2 : out;
    out = (x > 0.55f) ? 1.f : out;
    return out;
}

// ---------------- dtype detector ----------------
// Scan first 4096 bf16-interpreted elements of W_raw. Real bf16 data (|v|<1)
// never has exponent >= 0xC0. fp32 data read as u16 gives mantissa-garbage
// low halves -> ~25% of nonzero elements hit. 8192 bytes is within the
// buffer under both interpretations.
__global__ void srnn_detect_kernel(const uint16_t* canary, int* flag) {
    __shared__ int cnt;
    if (threadIdx.x == 0) cnt = 0;
    __syncthreads();
    int bad = 0;
    for (int i = threadIdx.x; i < 4096; i += 256) {
        uint16_t u = canary[i];
        int e = (u >> 7) & 0xFF;
        if (e >= 0xC0) bad++;
    }
    atomicAdd(&cnt, bad);
    __syncthreads();
    if (threadIdx.x == 0) flag[0] = (cnt >= 16) ? 1 : 0;
}

// ---------------- precompute per-(k,n) fused constants ----------------
// P layout: 11 SoA arrays of K*N floats:
// 0 gx, 1 1/(1+gx), 2 thr0 (=a_0+sum c_0), 3 grec, 4 grel,
// 5..7 amul_j (=ga_j*c_j), 8..10 ainv_j (=1/(1+ga_j))
__global__ void srnn_params_kernel(
    const void* a0, const void* ltd,
    const void* ltaE, const void* lcE, const void* c0E,
    const void* ltaI, const void* lcI, const void* c0I,
    const void* lbrecE, const void* lbrelE,
    const void* lbrecI, const void* lbrelI,
    const int* flag, float* P)
{
    const int f = flag[0];
    int idx = blockIdx.x * 256 + threadIdx.x;   // 0..K*N-1
    if (idx >= K_ * N_) return;
    int n = idx & (N_ - 1);
    int k = idx >> 9;
    float gx = DT_ / spf(loadf(ltd, idx, f));
    float thr0 = loadf(a0, idx, f);

    const void *lta, *lc, *c0, *lbrec, *lbrel;
    int nn;
    if (n < NE_) { nn = n;        lta = ltaE; lc = lcE; c0 = c0E; lbrec = lbrecE; lbrel = lbrelE; }
    else         { nn = n - NE_;  lta = ltaI; lc = lcI; c0 = c0I; lbrec = lbrecI; lbrel = lbrelI; }
    int base3 = (k * NE_ + nn) * MA_;
    int base1 = k * NE_ + nn;

    float amul[3], ainv[3];
    #pragma unroll
    for (int j = 0; j < 3; ++j) {
        float ga = DT_ / spf(loadf(lta, base3 + j, f));
        float c  = spf(loadf(lc, base3 + j, f));
        amul[j] = ga * c;
        ainv[j] = 1.f / (1.f + ga);
        thr0 += loadf(c0, base3 + j, f);
    }
    float grec = DT_ / spf(loadf(lbrec, base1, f));
    float grel = DT_ / spf(loadf(lbrel, base1, f));

    const int KN = K_ * N_;
    P[0*KN + idx] = gx;
    P[1*KN + idx] = 1.f / (1.f + gx);
    P[2*KN + idx] = thr0;
    P[3*KN + idx] = grec;
    P[4*KN + idx] = grel;
    P[5*KN + idx] = amul[0]; P[6*KN + idx] = amul[1]; P[7*KN + idx] = amul[2];
    P[8*KN + idx] = ainv[0]; P[9*KN + idx] = ainv[1]; P[10*KN + idx] = ainv[2];
}

// ---------------- W_effT: WT[k][m][n] = sign(m) * softplus(Wraw[k][n][m]) * mask ----------------
__global__ void srnn_weff_kernel(const void* Wraw, const void* mask, const int* flag, uint16_t* WT)
{
    __shared__ float tile[32][33];
    const int f = flag[0];
    int k = blockIdx.z, nt = blockIdx.y, mt = blockIdx.x;
    int tx = threadIdx.x & 31, ty = threadIdx.x >> 5;   // ty 0..7
    const size_t base = (size_t)k * N_ * N_;
    #pragma unroll
    for (int r = 0; r < 32; r += 8) {
        int n = nt * 32 + ty + r, m = mt * 32 + tx;
        size_t idx = base + (size_t)n * N_ + m;
        float w = spf(loadf(Wraw, idx, f)) * loadf(mask, idx, f);
        if (m >= NE_) w = -w;       // sign by SOURCE column m
        tile[ty + r][tx] = w;
    }
    __syncthreads();
    #pragma unroll
    for (int r = 0; r < 32; r += 8) {
        int m = mt * 32 + ty + r, n = nt * 32 + tx;
        WT[base + (size_t)m * N_ + n] = f2b(tile[tx][ty + r]);
    }
}

// ---------------- W_inT: WinT[k][i][n] = Win[k][n][i] ----------------
__global__ void srnn_wint_kernel(const void* Win, const int* flag, uint16_t* WinT)
{
    __shared__ float tile[32][33];
    const int f = flag[0];
    int k = blockIdx.z, nt = blockIdx.y, it = blockIdx.x;
    int tx = threadIdx.x & 31, ty = threadIdx.x >> 5;
    #pragma unroll
    for (int r = 0; r < 32; r += 8) {
        int n = nt * 32 + ty + r, i = it * 32 + tx;
        tile[ty + r][tx] = loadf(Win, ((size_t)k * N_ + n) * IN_ + i, f);
    }
    __syncthreads();
    #pragma unroll
    for (int r = 0; r < 32; r += 8) {
        int i = it * 32 + ty + r, n = nt * 32 + tx;
        WinT[((size_t)k * IN_ + i) * N_ + n] = f2b(tile[tx][ty + r]);
    }
}

// ---------------- main persistent-state kernel ----------------
// grid (128, 8): blockIdx.x = batch tile (8 cols), blockIdx.y = k. 256 threads.
// thread t owns n = 2t, 2t+1. Since NE*MA = 768 = 3*256, the a-offset formula
// 3n+j holds for BOTH the E and I regions; b at 1536+n, x at 2048+n.
__global__ __launch_bounds__(256, 2)
void srnn_main_kernel(const void* __restrict__ inputs,
                      const void* __restrict__ state,
                      const uint16_t* __restrict__ WT,
                      const uint16_t* __restrict__ WinT,
                      const float* __restrict__ P,
                      const int* __restrict__ readout,
                      const int* __restrict__ flag,
                      void* __restrict__ out)
{
    __shared__ float s_lds[N_ * SROW];    // 24 KB
    __shared__ float in_lds[IN_ * SROW];  // 6 KB

    const int f = flag[0];
    const int t = threadIdx.x;
    const int k = blockIdx.y;
    const int b0 = blockIdx.x * BT;
    const int n0 = 2 * t;

    // params for n0, n0+1
    const int KN = K_ * N_;
    float gx[2], ivgx[2], thr0[2], grec[2], grel[2], amul[2][3], ainv[2][3];
    #pragma unroll
    for (int u = 0; u < 2; ++u) {
        int pi = k * N_ + n0 + u;
        gx[u]   = P[0*KN + pi];  ivgx[u] = P[1*KN + pi];  thr0[u] = P[2*KN + pi];
        grec[u] = P[3*KN + pi];  grel[u] = P[4*KN + pi];
        amul[u][0] = P[5*KN + pi]; amul[u][1] = P[6*KN + pi]; amul[u][2] = P[7*KN + pi];
        ainv[u][0] = P[8*KN + pi]; ainv[u][1] = P[9*KN + pi]; ainv[u][2] = P[10*KN + pi];
    }

    // load state tile into registers (dtype-adaptive scalar loads; read once)
    float xv[2][BT], bv[2][BT], av[2][3][BT];
    #pragma unroll
    for (int bb = 0; bb < BT; ++bb) {
        const size_t sb = ((size_t)k * B_ + b0 + bb) * STATE_;
        #pragma unroll
        for (int u = 0; u < 2; ++u) {
            #pragma unroll
            for (int j = 0; j < 3; ++j)
                av[u][j][bb] = loadf(state, sb + (size_t)3 * (n0 + u) + j, f);
            bv[u][bb] = loadf(state, sb + 1536 + n0 + u, f);
            xv[u][bb] = loadf(state, sb + 2048 + n0 + u, f);
        }
    }

    // stage inputs tile (transposed) into LDS
    #pragma unroll
    for (int q = 0; q < 4; ++q) {
        int idx = t + q * 256;          // 0..1023
        int bb = idx >> 7, i = idx & 127;
        in_lds[i * SROW + bb] = loadf(inputs, (size_t)(b0 + bb) * IN_ + i, f);
    }
    __syncthreads();

    // in_cur GEMM: ic[u][bb] = sum_i WinT[k][i][n0+u] * in[b0+bb][i]
    float ic[2][BT];
    #pragma unroll
    for (int u = 0; u < 2; ++u)
        #pragma unroll
        for (int bb = 0; bb < BT; ++bb) ic[u][bb] = 0.f;
    {
        const uint32_t* wp = (const uint32_t*)(WinT + (size_t)k * IN_ * N_);
        #pragma unroll 2
        for (int i = 0; i < IN_; ++i) {
            uint32_t w2 = wp[i * 256 + t];
            float w0 = b2f((uint16_t)w2), w1 = b2f((uint16_t)(w2 >> 16));
            const float* srow = &in_lds[i * SROW];
            float s8[8];
            *(float4*)&s8[0] = *(const float4*)srow;
            *(float4*)&s8[4] = *(const float4*)(srow + 4);
            #pragma unroll
            for (int bb = 0; bb < BT; ++bb) {
                ic[0][bb] = fmaf(w0, s8[bb], ic[0][bb]);
                ic[1][bb] = fmaf(w1, s8[bb], ic[1][bb]);
            }
        }
    }

    const uint32_t* weffp = (const uint32_t*)(WT + (size_t)k * N_ * N_);

    for (int step = 0; step < UNFOLDS_; ++step) {
        // r,s from current state; update a,b with this r
        float sloc[2][BT];
        #pragma unroll
        for (int u = 0; u < 2; ++u) {
            #pragma unroll
            for (int bb = 0; bb < BT; ++bb) {
                float thr = thr0[u] + av[u][0][bb] + av[u][1][bb] + av[u][2][bb];
                float r = psig(xv[u][bb] - thr);
                sloc[u][bb] = r * bv[u][bb];
                av[u][0][bb] = fmaf(amul[u][0], r, av[u][0][bb]) * ainv[u][0];
                av[u][1][bb] = fmaf(amul[u][1], r, av[u][1][bb]) * ainv[u][1];
                av[u][2][bb] = fmaf(amul[u][2], r, av[u][2][bb]) * ainv[u][2];
                bv[u][bb] = (bv[u][bb] + grec[u]) / (1.f + grec[u] + grel[u] * r);
            }
        }
        __syncthreads();   // previous step's GEMM reads of s_lds are done
        #pragma unroll
        for (int u = 0; u < 2; ++u) {
            float* dst = &s_lds[(n0 + u) * SROW];
            #pragma unroll
            for (int bb = 0; bb < BT; ++bb) dst[bb] = sloc[u][bb];
        }
        __syncthreads();

        // GEMM: syn[n][bb] = ic + sum_m WeffT[m][n] * s[m][bb]
        float syn0[BT], syn1[BT];
        #pragma unroll
        for (int bb = 0; bb < BT; ++bb) { syn0[bb] = ic[0][bb]; syn1[bb] = ic[1][bb]; }
        #pragma unroll 4
        for (int m = 0; m < N_; ++m) {
            uint32_t w2 = weffp[m * 256 + t];    // coalesced: 2 bf16 for n0,n0+1
            float w0 = b2f((uint16_t)w2), w1 = b2f((uint16_t)(w2 >> 16));
            const float* srow = &s_lds[m * SROW];
            float s8[8];
            *(float4*)&s8[0] = *(const float4*)srow;      // wave-uniform -> LDS broadcast
            *(float4*)&s8[4] = *(const float4*)(srow + 4);
            #pragma unroll
            for (int bb = 0; bb < BT; ++bb) {
                syn0[bb] = fmaf(w0, s8[bb], syn0[bb]);
                syn1[bb] = fmaf(w1, s8[bb], syn1[bb]);
            }
        }
        // x update
        #pragma unroll
        for (int bb = 0; bb < BT; ++bb) {
            xv[0][bb] = fmaf(gx[0], syn0[bb], xv[0][bb]) * ivgx[0];
            xv[1][bb] = fmaf(gx[1], syn1[bb], xv[1][bb]) * ivgx[1];
        }
    }

    // final rate_syn (no state update)
    float rf[2][BT], sf[2][BT];
    #pragma unroll
    for (int u = 0; u < 2; ++u)
        #pragma unroll
        for (int bb = 0; bb < BT; ++bb) {
            float thr = thr0[u] + av[u][0][bb] + av[u][1][bb] + av[u][2][bb];
            float r = psig(xv[u][bb] - thr);
            rf[u][bb] = r;
            sf[u][bb] = r * bv[u][bb];
        }

    const int rid = readout[k];
    // ---- dtype-adaptive epilogue ----
    if (f) {
        float* outp = (float*)out;                     // [K][B][N]
        float* nst  = outp + (size_t)K_ * B_ * N_;     // [K][B][STATE]
        #pragma unroll
        for (int bb = 0; bb < BT; ++bb) {
            int b = b0 + bb;
            float o0, o1;
            if (rid == 0)      { o0 = sf[0][bb]; o1 = sf[1][bb]; }
            else if (rid == 1) { o0 = rf[0][bb]; o1 = rf[1][bb]; }
            else               { o0 = xv[0][bb]; o1 = xv[1][bb]; }
            float2 o2; o2.x = o0; o2.y = o1;
            *(float2*)(outp + ((size_t)k * B_ + b) * N_ + n0) = o2;

            float* st = nst + ((size_t)k * B_ + b) * STATE_;
            float2 a01; a01.x = av[0][0][bb]; a01.y = av[0][1][bb];
            float2 a23; a23.x = av[0][2][bb]; a23.y = av[1][0][bb];
            float2 a45; a45.x = av[1][1][bb]; a45.y = av[1][2][bb];
            *(float2*)(st + 6 * t + 0) = a01;
            *(float2*)(st + 6 * t + 2) = a23;
            *(float2*)(st + 6 * t + 4) = a45;
            float2 b2v; b2v.x = bv[0][bb]; b2v.y = bv[1][bb];
            *(float2*)(st + 1536 + n0) = b2v;
            float2 x2v; x2v.x = xv[0][bb]; x2v.y = xv[1][bb];
            *(float2*)(st + 2048 + n0) = x2v;
        }
    } else {
        uint16_t* outp = (uint16_t*)out;               // [K][B][N]
        uint16_t* nst  = outp + (size_t)K_ * B_ * N_;  // [K][B][STATE]
        #pragma unroll
        for (int bb = 0; bb < BT; ++bb) {
            int b = b0 + bb;
            float o0, o1;
            if (rid == 0)      { o0 = sf[0][bb]; o1 = sf[1][bb]; }
            else if (rid == 1) { o0 = rf[0][bb]; o1 = rf[1][bb]; }
            else               { o0 = xv[0][bb]; o1 = xv[1][bb]; }
            *(uint32_t*)(outp + ((size_t)k * B_ + b) * N_ + n0) = pack2(f2b(o0), f2b(o1));

            uint16_t* st = nst + ((size_t)k * B_ + b) * STATE_;
            uint32_t* ap = (uint32_t*)(st + 6 * t);
            ap[0] = pack2(f2b(av[0][0][bb]), f2b(av[0][1][bb]));
            ap[1] = pack2(f2b(av[0][2][bb]), f2b(av[1][0][bb]));
            ap[2] = pack2(f2b(av[1][1][bb]), f2b(av[1][2][bb]));
            *(uint32_t*)(st + 1536 + n0) = pack2(f2b(bv[0][bb]), f2b(bv[1][bb]));
            *(uint32_t*)(st + 2048 + n0) = pack2(f2b(xv[0][bb]), f2b(xv[1][bb]));
        }
    }
}

extern "C" void kernel_launch(void* const* d_in, const int* in_sizes, int n_in,
                              void* d_out, int out_size, void* d_ws, size_t ws_size,
                              hipStream_t stream) {
    const void* inputs = d_in[0];
    const void* state  = d_in[1];
    const void* Wraw   = d_in[2];
    const void* mask   = d_in[3];
    const void* Win    = d_in[4];
    const void* a0     = d_in[5];
    const void* ltd    = d_in[6];
    const void* ltaE   = d_in[7];
    const void* lcE    = d_in[8];
    const void* c0E    = d_in[9];
    const void* ltaI   = d_in[10];
    const void* lcI    = d_in[11];
    const void* c0I    = d_in[12];
    const void* lbrecE = d_in[13];
    const void* lbrelE = d_in[14];
    const void* lbrecI = d_in[15];
    const void* lbrelI = d_in[16];
    const int* readout = (const int*)d_in[17];

    // workspace: flag (256 B) | P (180224 B) | WeffT bf16 (4 MiB) | WinT bf16 (1 MiB)
    int* flag = (int*)d_ws;
    float* P = (float*)((char*)d_ws + 256);
    uint16_t* WT   = (uint16_t*)((char*)d_ws + 256 + 180224);
    uint16_t* WinT = (uint16_t*)((char*)d_ws + 256 + 180224 + (size_t)K_ * N_ * N_ * 2);

    srnn_detect_kernel<<<dim3(1), dim3(256), 0, stream>>>((const uint16_t*)Wraw, flag);
    srnn_params_kernel<<<dim3((K_ * N_ + 255) / 256), dim3(256), 0, stream>>>(
        a0, ltd, ltaE, lcE, c0E, ltaI, lcI, c0I, lbrecE, lbrelE, lbrecI, lbrelI, flag, P);
    srnn_weff_kernel<<<dim3(N_ / 32, N_ / 32, K_), dim3(256), 0, stream>>>(Wraw, mask, flag, WT);
    srnn_wint_kernel<<<dim3(IN_ / 32, N_ / 32, K_), dim3(256), 0, stream>>>(Win, flag, WinT);
    srnn_main_kernel<<<dim3(B_ / BT, K_), dim3(256), 0, stream>>>(
        inputs, state, WT, WinT, P, readout, flag, d_out);
}

// Round 4
// 371.194 us; speedup vs baseline: 1.8706x; 1.8706x over previous
//
#include <hip/hip_runtime.h>
#include <stdint.h>

#define K_ 8
#define N_ 512
#define NE_ 256
#define MA_ 3
#define IN_ 128
#define B_ 1024
#define STATE_ 2560
#define UNFOLDS_ 6
#define DT_ (0.04f / 6.0f)

typedef __attribute__((ext_vector_type(8))) short short8;   // 8 bf16 (4 VGPRs)
typedef __attribute__((ext_vector_type(4))) float floatx4;  // MFMA C/D

__device__ __forceinline__ float b2f(uint16_t u) {
    union { uint32_t i; float f; } v; v.i = ((uint32_t)u) << 16; return v.f;
}
__device__ __forceinline__ uint16_t f2b(float f) {
    union { float f; uint32_t i; } v; v.f = f;
    uint32_t i = v.i;
    uint32_t r = i + 0x7FFFu + ((i >> 16) & 1u);   // RTNE
    return (uint16_t)(r >> 16);
}
__device__ __forceinline__ uint32_t pack2(uint16_t lo, uint16_t hi) {
    return (uint32_t)lo | ((uint32_t)hi << 16);
}
// dtype-adaptive load: f32!=0 -> buffer is float32, else bf16
__device__ __forceinline__ float loadf(const void* p, size_t i, int f32) {
    return f32 ? ((const float*)p)[i] : b2f(((const uint16_t*)p)[i]);
}
__device__ __forceinline__ float spf(float x) {   // softplus, stable
    return (x > 20.f) ? x : log1pf(expf(x));
}
__device__ __forceinline__ float psig(float x) {
    // S_a=0.9, S_c=0: x1=-0.55 x2=-0.45 x3=0.45 x4=0.55, k=5
    float t1 = x + 0.55f;
    float q1 = 5.f * t1 * t1;
    float t2 = x - 0.55f;
    float q2 = 1.f - 5.f * t2 * t2;
    float out = (x < -0.55f) ? 0.f : q1;
    out = (x >= -0.45f) ? (x + 0.5f) : out;
    out = (x > 0.45f) ? q2 : out;
    out = (x > 0.55f) ? 1.f : out;
    return out;
}

// ---------------- dtype detector (unchanged, verified working) ----------------
__global__ void srnn_detect_kernel(const uint16_t* canary, int* flag) {
    __shared__ int cnt;
    if (threadIdx.x == 0) cnt = 0;
    __syncthreads();
    int bad = 0;
    for (int i = threadIdx.x; i < 4096; i += 256) {
        uint16_t u = canary[i];
        int e = (u >> 7) & 0xFF;
        if (e >= 0xC0) bad++;
    }
    atomicAdd(&cnt, bad);
    __syncthreads();
    if (threadIdx.x == 0) flag[0] = (cnt >= 16) ? 1 : 0;
}

// ---------------- per-(k,n) fused constants (unchanged) ----------------
__global__ void srnn_params_kernel(
    const void* a0, const void* ltd,
    const void* ltaE, const void* lcE, const void* c0E,
    const void* ltaI, const void* lcI, const void* c0I,
    const void* lbrecE, const void* lbrelE,
    const void* lbrecI, const void* lbrelI,
    const int* flag, float* P)
{
    const int f = flag[0];
    int idx = blockIdx.x * 256 + threadIdx.x;
    if (idx >= K_ * N_) return;
    int n = idx & (N_ - 1);
    int k = idx >> 9;
    float gx = DT_ / spf(loadf(ltd, idx, f));
    float thr0 = loadf(a0, idx, f);

    const void *lta, *lc, *c0, *lbrec, *lbrel;
    int nn;
    if (n < NE_) { nn = n;        lta = ltaE; lc = lcE; c0 = c0E; lbrec = lbrecE; lbrel = lbrelE; }
    else         { nn = n - NE_;  lta = ltaI; lc = lcI; c0 = c0I; lbrec = lbrecI; lbrel = lbrelI; }
    int base3 = (k * NE_ + nn) * MA_;
    int base1 = k * NE_ + nn;

    float amul[3], ainv[3];
    #pragma unroll
    for (int j = 0; j < 3; ++j) {
        float ga = DT_ / spf(loadf(lta, base3 + j, f));
        float c  = spf(loadf(lc, base3 + j, f));
        amul[j] = ga * c;
        ainv[j] = 1.f / (1.f + ga);
        thr0 += loadf(c0, base3 + j, f);
    }
    float grec = DT_ / spf(loadf(lbrec, base1, f));
    float grel = DT_ / spf(loadf(lbrel, base1, f));

    const int KN = K_ * N_;
    P[0*KN + idx] = gx;
    P[1*KN + idx] = 1.f / (1.f + gx);
    P[2*KN + idx] = thr0;
    P[3*KN + idx] = grec;
    P[4*KN + idx] = grel;
    P[5*KN + idx] = amul[0]; P[6*KN + idx] = amul[1]; P[7*KN + idx] = amul[2];
    P[8*KN + idx] = ainv[0]; P[9*KN + idx] = ainv[1]; P[10*KN + idx] = ainv[2];
}

// ---------------- W_eff swizzled into MFMA A-fragment order ----------------
// Wsw[k][ntile 0..31][ks 0..15][lane 0..63][j 0..7] (bf16), where the A-frag
// element for 16x16x32 is A[row = lane&15][kk = (lane>>4)*8 + j]:
//   row -> dest neuron n = nt*16 + (lane&15)
//   kk  -> src  neuron m = ks*32 + (lane>>4)*8 + j
// Block = (nt, k): stage 16x512 W_eff rows in LDS (coalesced), scatter-gather out.
__global__ __launch_bounds__(256) void srnn_wsw_kernel(
    const void* __restrict__ Wraw, const void* __restrict__ mask,
    const int* __restrict__ flag, uint16_t* __restrict__ Wsw)
{
    __shared__ float tile[16 * 516];   // rows n (16) x m (512), stride 516
    const int f = flag[0];
    const int nt = blockIdx.x, k = blockIdx.y, t = threadIdx.x;
    const size_t base = (size_t)k * N_ * N_ + (size_t)nt * 16 * N_;
    #pragma unroll
    for (int i = 0; i < 32; ++i) {
        int idx = i * 256 + t;          // 0..8191
        int row = idx >> 9, m = idx & 511;
        size_t gi = base + (size_t)row * N_ + m;
        float w = spf(loadf(Wraw, gi, f)) * loadf(mask, gi, f);
        if (m >= NE_) w = -w;           // sign by SOURCE column m
        tile[row * 516 + m] = w;
    }
    __syncthreads();
    uint16_t* outb = Wsw + ((size_t)k * 32 + nt) * (16 * 64 * 8);
    #pragma unroll
    for (int i = 0; i < 4; ++i) {
        int id = i * 256 + t;           // frag-lane id: 0..1023 = ks*64 + L
        int ks = id >> 6, L = id & 63;
        int row = L & 15, quad = L >> 4;
        const float* src = &tile[row * 516 + ks * 32 + quad * 8];
        uint4 v;
        v.x = pack2(f2b(src[0]), f2b(src[1]));
        v.y = pack2(f2b(src[2]), f2b(src[3]));
        v.z = pack2(f2b(src[4]), f2b(src[5]));
        v.w = pack2(f2b(src[6]), f2b(src[7]));
        *(uint4*)(outb + (size_t)id * 8) = v;
    }
}

// ---------------- W_inT: WinT[k][i][n] bf16 (unchanged) ----------------
__global__ void srnn_wint_kernel(const void* Win, const int* flag, uint16_t* WinT)
{
    __shared__ float tile[32][33];
    const int f = flag[0];
    int k = blockIdx.z, nt = blockIdx.y, it = blockIdx.x;
    int tx = threadIdx.x & 31, ty = threadIdx.x >> 5;
    #pragma unroll
    for (int r = 0; r < 32; r += 8) {
        int n = nt * 32 + ty + r, i = it * 32 + tx;
        tile[ty + r][tx] = loadf(Win, ((size_t)k * N_ + n) * IN_ + i, f);
    }
    __syncthreads();
    #pragma unroll
    for (int r = 0; r < 32; r += 8) {
        int i = it * 32 + ty + r, n = nt * 32 + tx;
        WinT[((size_t)k * IN_ + i) * N_ + n] = f2b(tile[tx][ty + r]);
    }
}

// ---------------- in_cur to global: icg[k][b][n] f32 (round-3 GEMM code) ----------------
__global__ __launch_bounds__(256) void srnn_ic_kernel(
    const void* __restrict__ inputs, const uint16_t* __restrict__ WinT,
    const int* __restrict__ flag, float* __restrict__ icg)
{
    __shared__ float in_lds[IN_ * 12];
    const int f = flag[0];
    const int t = threadIdx.x;
    const int k = blockIdx.y;
    const int b0 = blockIdx.x * 8;
    const int n0 = 2 * t;
    #pragma unroll
    for (int q = 0; q < 4; ++q) {
        int idx = t + q * 256;
        int bb = idx >> 7, i = idx & 127;
        in_lds[i * 12 + bb] = loadf(inputs, (size_t)(b0 + bb) * IN_ + i, f);
    }
    __syncthreads();
    float ic0[8], ic1[8];
    #pragma unroll
    for (int bb = 0; bb < 8; ++bb) { ic0[bb] = 0.f; ic1[bb] = 0.f; }
    const uint32_t* wp = (const uint32_t*)(WinT + (size_t)k * IN_ * N_);
    #pragma unroll 2
    for (int i = 0; i < IN_; ++i) {
        uint32_t w2 = wp[i * 256 + t];
        float w0 = b2f((uint16_t)w2), w1 = b2f((uint16_t)(w2 >> 16));
        const float* srow = &in_lds[i * 12];
        float s8[8];
        *(float4*)&s8[0] = *(const float4*)srow;
        *(float4*)&s8[4] = *(const float4*)(srow + 4);
        #pragma unroll
        for (int bb = 0; bb < 8; ++bb) {
            ic0[bb] = fmaf(w0, s8[bb], ic0[bb]);
            ic1[bb] = fmaf(w1, s8[bb], ic1[bb]);
        }
    }
    #pragma unroll
    for (int bb = 0; bb < 8; ++bb) {
        float2 v; v.x = ic0[bb]; v.y = ic1[bb];
        *(float2*)(icg + ((size_t)k * B_ + b0 + bb) * N_ + n0) = v;
    }
}

// ---------------- main persistent-state MFMA kernel ----------------
// grid 512 linear: k = bx&7 (XCD-pinned), btile = bx>>3 (16 batch cols).
// 512 threads = 8 waves. Elementwise: thread t owns n=t, all 16 b-cols.
// GEMM: wave w owns n-rows [64w, 64w+64) = 4 MFMA n-tiles; per k-step one
// B-frag (ds_read_b128 from transposed bf16 s) feeds 4 MFMAs whose A-frags
// stream from the pre-swizzled Wsw (global_load_dwordx4, L2-resident).
// syn round-trips through LDS (C-layout -> n-per-thread layout).
__global__ __launch_bounds__(512, 1)
void srnn_main_kernel(const void* __restrict__ state,
                      const uint16_t* __restrict__ Wsw,
                      const float* __restrict__ icg,
                      const float* __restrict__ P,
                      const int* __restrict__ readout,
                      const int* __restrict__ flag,
                      void* __restrict__ out)
{
    __shared__ __align__(16) uint16_t sT[16 * 520];   // s transposed [b][m] bf16, stride 520
    __shared__ __align__(16) float synT[16 * 516];    // syn transposed [b][n] f32, stride 516

    const int f = flag[0];
    const int t = threadIdx.x;            // 0..511
    const int k = blockIdx.x & 7;
    const int b0 = (blockIdx.x >> 3) * 16;
    const int n = t;                      // elementwise ownership
    const int lane = t & 63, w = t >> 6;
    const int bq = lane & 15, quad = lane >> 4;

    // params for n
    const int KN = K_ * N_;
    const int pi = k * N_ + n;
    const float gx = P[0*KN+pi], ivgx = P[1*KN+pi], thr0 = P[2*KN+pi];
    const float grec = P[3*KN+pi], grel = P[4*KN+pi];
    const float amul0 = P[5*KN+pi], amul1 = P[6*KN+pi], amul2 = P[7*KN+pi];
    const float ainv0 = P[8*KN+pi], ainv1 = P[9*KN+pi], ainv2 = P[10*KN+pi];

    // state + ic (16 batch cols each). NE*MA=768=3*256 => a-offset 3n+j valid for all n.
    float a0v[16], a1v[16], a2v[16], bv[16], xv[16], ic[16];
    #pragma unroll
    for (int bb = 0; bb < 16; ++bb) {
        size_t sb = ((size_t)k * B_ + b0 + bb) * STATE_;
        a0v[bb] = loadf(state, sb + 3 * n + 0, f);
        a1v[bb] = loadf(state, sb + 3 * n + 1, f);
        a2v[bb] = loadf(state, sb + 3 * n + 2, f);
        bv[bb]  = loadf(state, sb + 1536 + n, f);
        xv[bb]  = loadf(state, sb + 2048 + n, f);
        ic[bb]  = icg[((size_t)k * B_ + b0 + bb) * N_ + n];
    }

    // per-lane GEMM base pointers
    const uint16_t* wbase = Wsw + (size_t)k * 32 * 16 * 64 * 8;          // this net's frags
    const uint16_t* ape = wbase + ((size_t)(4 * w) * 16 * 64 + lane) * 8; // nt=0, ks=0 frag
    const uint16_t* bpe = sT + bq * 520 + quad * 8;                       // B-frag base

    for (int step = 0; step < UNFOLDS_; ++step) {
        // elementwise: r from (a,x) at step start; update a,b; stage s (bf16, transposed)
        #pragma unroll
        for (int bb = 0; bb < 16; ++bb) {
            float thr = thr0 + a0v[bb] + a1v[bb] + a2v[bb];
            float r = psig(xv[bb] - thr);
            float s = r * bv[bb];
            a0v[bb] = fmaf(amul0, r, a0v[bb]) * ainv0;
            a1v[bb] = fmaf(amul1, r, a1v[bb]) * ainv1;
            a2v[bb] = fmaf(amul2, r, a2v[bb]) * ainv2;
            bv[bb] = (bv[bb] + grec) / (1.f + grec + grel * r);
            sT[bb * 520 + n] = f2b(s);
        }
        __syncthreads();

        // GEMM: 4 n-tiles x 16 k-steps of mfma_f32_16x16x32_bf16
        floatx4 c0 = {0.f, 0.f, 0.f, 0.f}, c1 = c0, c2 = c0, c3 = c0;
        #pragma unroll 2
        for (int ks = 0; ks < 16; ++ks) {
            short8 bf = *(const short8*)(bpe + ks * 32);
            short8 af0 = *(const short8*)(ape + ks * 512);
            short8 af1 = *(const short8*)(ape + 8192 + ks * 512);
            short8 af2 = *(const short8*)(ape + 16384 + ks * 512);
            short8 af3 = *(const short8*)(ape + 24576 + ks * 512);
            c0 = __builtin_amdgcn_mfma_f32_16x16x32_bf16(af0, bf, c0, 0, 0, 0);
            c1 = __builtin_amdgcn_mfma_f32_16x16x32_bf16(af1, bf, c1, 0, 0, 0);
            c2 = __builtin_amdgcn_mfma_f32_16x16x32_bf16(af2, bf, c2, 0, 0, 0);
            c3 = __builtin_amdgcn_mfma_f32_16x16x32_bf16(af3, bf, c3, 0, 0, 0);
        }
        // C/D layout: col = lane&15 (=b), row = quad*4 + reg (+16 per n-tile)
        {
            const int nb = w * 64 + quad * 4;
            *(floatx4*)(&synT[bq * 516 + nb +  0]) = c0;
            *(floatx4*)(&synT[bq * 516 + nb + 16]) = c1;
            *(floatx4*)(&synT[bq * 516 + nb + 32]) = c2;
            *(floatx4*)(&synT[bq * 516 + nb + 48]) = c3;
        }
        __syncthreads();

        // x update (n-per-thread layout)
        #pragma unroll
        for (int bb = 0; bb < 16; ++bb) {
            float syn = synT[bb * 516 + n] + ic[bb];
            xv[bb] = fmaf(gx, syn, xv[bb]) * ivgx;
        }
    }

    // final rate_syn + epilogue (dtype-adaptive)
    const int rid = readout[k];
    if (f) {
        float* outp = (float*)out;
        float* nst = outp + (size_t)K_ * B_ * N_;
        #pragma unroll
        for (int bb = 0; bb < 16; ++bb) {
            float thr = thr0 + a0v[bb] + a1v[bb] + a2v[bb];
            float r = psig(xv[bb] - thr);
            float s = r * bv[bb];
            float o = (rid == 0) ? s : ((rid == 1) ? r : xv[bb]);
            size_t ob = (size_t)k * B_ + b0 + bb;
            outp[ob * N_ + n] = o;
            float* st = nst + ob * STATE_;
            st[3 * n + 0] = a0v[bb];
            st[3 * n + 1] = a1v[bb];
            st[3 * n + 2] = a2v[bb];
            st[1536 + n] = bv[bb];
            st[2048 + n] = xv[bb];
        }
    } else {
        uint16_t* outp = (uint16_t*)out;
        uint16_t* nst = outp + (size_t)K_ * B_ * N_;
        #pragma unroll
        for (int bb = 0; bb < 16; ++bb) {
            float thr = thr0 + a0v[bb] + a1v[bb] + a2v[bb];
            float r = psig(xv[bb] - thr);
            float s = r * bv[bb];
            float o = (rid == 0) ? s : ((rid == 1) ? r : xv[bb]);
            size_t ob = (size_t)k * B_ + b0 + bb;
            outp[ob * N_ + n] = f2b(o);
            uint16_t* st = nst + ob * STATE_;
            st[3 * n + 0] = f2b(a0v[bb]);
            st[3 * n + 1] = f2b(a1v[bb]);
            st[3 * n + 2] = f2b(a2v[bb]);
            st[1536 + n] = f2b(bv[bb]);
            st[2048 + n] = f2b(xv[bb]);
        }
    }
}

extern "C" void kernel_launch(void* const* d_in, const int* in_sizes, int n_in,
                              void* d_out, int out_size, void* d_ws, size_t ws_size,
                              hipStream_t stream) {
    const void* inputs = d_in[0];
    const void* state  = d_in[1];
    const void* Wraw   = d_in[2];
    const void* mask   = d_in[3];
    const void* Win    = d_in[4];
    const void* a0     = d_in[5];
    const void* ltd    = d_in[6];
    const void* ltaE   = d_in[7];
    const void* lcE    = d_in[8];
    const void* c0E    = d_in[9];
    const void* ltaI   = d_in[10];
    const void* lcI    = d_in[11];
    const void* c0I    = d_in[12];
    const void* lbrecE = d_in[13];
    const void* lbrelE = d_in[14];
    const void* lbrecI = d_in[15];
    const void* lbrelI = d_in[16];
    const int* readout = (const int*)d_in[17];

    // workspace layout (all 16B-aligned):
    // flag 256 B | P 180224 B | Wsw 4 MiB | WinT 1 MiB | icg 16 MiB  (~21.4 MiB)
    char* ws = (char*)d_ws;
    int* flag      = (int*)ws;
    float* P       = (float*)(ws + 256);
    uint16_t* Wsw  = (uint16_t*)(ws + 256 + 180224);
    uint16_t* WinT = (uint16_t*)(ws + 256 + 180224 + 4194304);
    float* icg     = (float*)(ws + 256 + 180224 + 4194304 + 1048576);

    srnn_detect_kernel<<<dim3(1), dim3(256), 0, stream>>>((const uint16_t*)Wraw, flag);
    srnn_params_kernel<<<dim3(16), dim3(256), 0, stream>>>(
        a0, ltd, ltaE, lcE, c0E, ltaI, lcI, c0I, lbrecE, lbrelE, lbrecI, lbrelI, flag, P);
    srnn_wsw_kernel<<<dim3(32, 8), dim3(256), 0, stream>>>(Wraw, mask, flag, Wsw);
    srnn_wint_kernel<<<dim3(IN_ / 32, N_ / 32, K_), dim3(256), 0, stream>>>(Win, flag, WinT);
    srnn_ic_kernel<<<dim3(B_ / 8, K_), dim3(256), 0, stream>>>(inputs, WinT, flag, icg);
    srnn_main_kernel<<<dim3(512), dim3(512), 0, stream>>>(
        state, Wsw, icg, P, readout, flag, d_out);
}

// Round 5
// 343.812 us; speedup vs baseline: 2.0196x; 1.0796x over previous
//
#include <hip/hip_runtime.h>
#include <stdint.h>

#define K_ 8
#define N_ 512
#define NE_ 256
#define MA_ 3
#define IN_ 128
#define B_ 1024
#define STATE_ 2560
#define UNFOLDS_ 6
#define DT_ (0.04f / 6.0f)

typedef __attribute__((ext_vector_type(8))) short short8;   // 8 bf16 (4 VGPRs)
typedef __attribute__((ext_vector_type(4))) float floatx4;  // MFMA C/D

__device__ __forceinline__ float b2f(uint16_t u) {
    union { uint32_t i; float f; } v; v.i = ((uint32_t)u) << 16; return v.f;
}
__device__ __forceinline__ uint16_t f2b(float f) {
    union { float f; uint32_t i; } v; v.f = f;
    uint32_t i = v.i;
    uint32_t r = i + 0x7FFFu + ((i >> 16) & 1u);   // RTNE
    return (uint16_t)(r >> 16);
}
__device__ __forceinline__ uint32_t pack2(uint16_t lo, uint16_t hi) {
    return (uint32_t)lo | ((uint32_t)hi << 16);
}
// dtype-adaptive load: f32!=0 -> buffer is float32, else bf16
__device__ __forceinline__ float loadf(const void* p, size_t i, int f32) {
    return f32 ? ((const float*)p)[i] : b2f(((const uint16_t*)p)[i]);
}
// non-temporal variant (state/input streams must not evict Wsw from L2)
__device__ __forceinline__ float ntloadf(const void* p, size_t i, int f32) {
    return f32 ? __builtin_nontemporal_load((const float*)p + i)
               : b2f(__builtin_nontemporal_load((const uint16_t*)p + i));
}
__device__ __forceinline__ float spf(float x) {   // softplus, stable
    return (x > 20.f) ? x : log1pf(expf(x));
}
__device__ __forceinline__ float psig(float x) {
    // S_a=0.9, S_c=0: x1=-0.55 x2=-0.45 x3=0.45 x4=0.55, k=5
    float t1 = x + 0.55f;
    float q1 = 5.f * t1 * t1;
    float t2 = x - 0.55f;
    float q2 = 1.f - 5.f * t2 * t2;
    float out = (x < -0.55f) ? 0.f : q1;
    out = (x >= -0.45f) ? (x + 0.5f) : out;
    out = (x > 0.45f) ? q2 : out;
    out = (x > 0.55f) ? 1.f : out;
    return out;
}

// ---------------- dtype detector (verified working) ----------------
__global__ void srnn_detect_kernel(const uint16_t* canary, int* flag) {
    __shared__ int cnt;
    if (threadIdx.x == 0) cnt = 0;
    __syncthreads();
    int bad = 0;
    for (int i = threadIdx.x; i < 4096; i += 256) {
        uint16_t u = canary[i];
        int e = (u >> 7) & 0xFF;
        if (e >= 0xC0) bad++;
    }
    atomicAdd(&cnt, bad);
    __syncthreads();
    if (threadIdx.x == 0) flag[0] = (cnt >= 16) ? 1 : 0;
}

// ---------------- per-(k,n) fused constants (unchanged) ----------------
__global__ void srnn_params_kernel(
    const void* a0, const void* ltd,
    const void* ltaE, const void* lcE, const void* c0E,
    const void* ltaI, const void* lcI, const void* c0I,
    const void* lbrecE, const void* lbrelE,
    const void* lbrecI, const void* lbrelI,
    const int* flag, float* P)
{
    const int f = flag[0];
    int idx = blockIdx.x * 256 + threadIdx.x;
    if (idx >= K_ * N_) return;
    int n = idx & (N_ - 1);
    int k = idx >> 9;
    float gx = DT_ / spf(loadf(ltd, idx, f));
    float thr0 = loadf(a0, idx, f);

    const void *lta, *lc, *c0, *lbrec, *lbrel;
    int nn;
    if (n < NE_) { nn = n;        lta = ltaE; lc = lcE; c0 = c0E; lbrec = lbrecE; lbrel = lbrelE; }
    else         { nn = n - NE_;  lta = ltaI; lc = lcI; c0 = c0I; lbrec = lbrecI; lbrel = lbrelI; }
    int base3 = (k * NE_ + nn) * MA_;
    int base1 = k * NE_ + nn;

    float amul[3], ainv[3];
    #pragma unroll
    for (int j = 0; j < 3; ++j) {
        float ga = DT_ / spf(loadf(lta, base3 + j, f));
        float c  = spf(loadf(lc, base3 + j, f));
        amul[j] = ga * c;
        ainv[j] = 1.f / (1.f + ga);
        thr0 += loadf(c0, base3 + j, f);
    }
    float grec = DT_ / spf(loadf(lbrec, base1, f));
    float grel = DT_ / spf(loadf(lbrel, base1, f));

    const int KN = K_ * N_;
    P[0*KN + idx] = gx;
    P[1*KN + idx] = 1.f / (1.f + gx);
    P[2*KN + idx] = thr0;
    P[3*KN + idx] = grec;
    P[4*KN + idx] = grel;
    P[5*KN + idx] = amul[0]; P[6*KN + idx] = amul[1]; P[7*KN + idx] = amul[2];
    P[8*KN + idx] = ainv[0]; P[9*KN + idx] = ainv[1]; P[10*KN + idx] = ainv[2];
}

// ---------------- W_eff swizzled into MFMA A-fragment order (verified) ----------------
// Wsw[k][nt 0..31][ks 0..15][lane 0..63][j 0..7] (bf16):
//   A[row = lane&15][kk = (lane>>4)*8 + j]; n = nt*16+row, m = ks*32+kk.
__global__ __launch_bounds__(256) void srnn_wsw_kernel(
    const void* __restrict__ Wraw, const void* __restrict__ mask,
    const int* __restrict__ flag, uint16_t* __restrict__ Wsw)
{
    __shared__ float tile[16 * 516];
    const int f = flag[0];
    const int nt = blockIdx.x, k = blockIdx.y, t = threadIdx.x;
    const size_t base = (size_t)k * N_ * N_ + (size_t)nt * 16 * N_;
    #pragma unroll
    for (int i = 0; i < 32; ++i) {
        int idx = i * 256 + t;
        int row = idx >> 9, m = idx & 511;
        size_t gi = base + (size_t)row * N_ + m;
        float w = spf(ntloadf(Wraw, gi, f)) * ntloadf(mask, gi, f);
        if (m >= NE_) w = -w;           // sign by SOURCE column m
        tile[row * 516 + m] = w;
    }
    __syncthreads();
    uint16_t* outb = Wsw + ((size_t)k * 32 + nt) * (16 * 64 * 8);
    #pragma unroll
    for (int i = 0; i < 4; ++i) {
        int id = i * 256 + t;           // 0..1023 = ks*64 + L
        int ks = id >> 6, L = id & 63;
        int row = L & 15, quad = L >> 4;
        const float* src = &tile[row * 516 + ks * 32 + quad * 8];
        uint4 v;
        v.x = pack2(f2b(src[0]), f2b(src[1]));
        v.y = pack2(f2b(src[2]), f2b(src[3]));
        v.z = pack2(f2b(src[4]), f2b(src[5]));
        v.w = pack2(f2b(src[6]), f2b(src[7]));
        *(uint4*)(outb + (size_t)id * 8) = v;
    }
}

// ---------------- W_in swizzled into MFMA A-fragment order ----------------
// Winsw[k][nt 0..31][ks 0..3][lane][8] (bf16): same mapping, kk-range = IN (128).
__global__ __launch_bounds__(256) void srnn_winsw_kernel(
    const void* __restrict__ Win, const int* __restrict__ flag,
    uint16_t* __restrict__ Winsw)
{
    __shared__ float tile[16 * 132];
    const int f = flag[0];
    const int nt = blockIdx.x, k = blockIdx.y, t = threadIdx.x;
    const size_t base = (size_t)k * N_ * IN_ + (size_t)nt * 16 * IN_;
    #pragma unroll
    for (int i = 0; i < 8; ++i) {
        int idx = i * 256 + t;          // 0..2047
        int row = idx >> 7, c = idx & 127;
        tile[row * 132 + c] = ntloadf(Win, base + (size_t)row * IN_ + c, f);
    }
    __syncthreads();
    uint16_t* outb = Winsw + ((size_t)k * 32 + nt) * (4 * 64 * 8);
    {
        int id = t;                     // 0..255 = ks*64 + L
        int ks = id >> 6, L = id & 63;
        int row = L & 15, quad = L >> 4;
        const float* src = &tile[row * 132 + ks * 32 + quad * 8];
        uint4 v;
        v.x = pack2(f2b(src[0]), f2b(src[1]));
        v.y = pack2(f2b(src[2]), f2b(src[3]));
        v.z = pack2(f2b(src[4]), f2b(src[5]));
        v.w = pack2(f2b(src[6]), f2b(src[7]));
        *(uint4*)(outb + (size_t)id * 8) = v;
    }
}

// ---------------- main persistent-state MFMA kernel ----------------
// grid 512: k = bx&7 (XCD-pinned), btile = bx>>3 (16 cols). 512 thr = 8 waves.
// Prologue: in_cur = MFMA(Winsw, inputs) -> ic[16] regs (via synT round-trip).
// Step loop (verified round-4 structure): elementwise -> sT(bf16,transposed)
// -> MFMA(Wsw from L2, sT) -> synT -> x update. State stream is non-temporal
// so Wsw stays L2-resident.
__global__ __launch_bounds__(512, 1)
void srnn_main_kernel(const void* __restrict__ state,
                      const void* __restrict__ inputs,
                      const uint16_t* __restrict__ Wsw,
                      const uint16_t* __restrict__ Winsw,
                      const float* __restrict__ P,
                      const int* __restrict__ readout,
                      const int* __restrict__ flag,
                      void* __restrict__ out)
{
    __shared__ __align__(16) uint16_t sT[16 * 520];   // [b][m] bf16, stride 520
    __shared__ __align__(16) float synT[16 * 516];    // [b][n] f32, stride 516

    const int f = flag[0];
    const int t = threadIdx.x;            // 0..511
    const int k = blockIdx.x & 7;
    const int b0 = (blockIdx.x >> 3) * 16;
    const int n = t;                      // elementwise ownership
    const int lane = t & 63, w = t >> 6;
    const int bq = lane & 15, quad = lane >> 4;

    // params for n
    const int KN = K_ * N_;
    const int pi = k * N_ + n;
    const float gx = P[0*KN+pi], ivgx = P[1*KN+pi], thr0 = P[2*KN+pi];
    const float grec = P[3*KN+pi], grel = P[4*KN+pi];
    const float amul0 = P[5*KN+pi], amul1 = P[6*KN+pi], amul2 = P[7*KN+pi];
    const float ainv0 = P[8*KN+pi], ainv1 = P[9*KN+pi], ainv2 = P[10*KN+pi];

    // stage inputs tile (transposed, bf16) into sT for the ic GEMM
    #pragma unroll
    for (int q = 0; q < 4; ++q) {
        int idx = q * 512 + t;            // 0..2047
        int bb = idx >> 7, i = idx & 127;
        sT[bb * 520 + i] = f2b(ntloadf(inputs, (size_t)(b0 + bb) * IN_ + i, f));
    }

    // state tile into registers (non-temporal; NE*MA=768=3*256 => 3n+j valid for all n)
    float a0v[16], a1v[16], a2v[16], bv[16], xv[16], ic[16];
    #pragma unroll
    for (int bb = 0; bb < 16; ++bb) {
        size_t sb = ((size_t)k * B_ + b0 + bb) * STATE_;
        a0v[bb] = ntloadf(state, sb + 3 * n + 0, f);
        a1v[bb] = ntloadf(state, sb + 3 * n + 1, f);
        a2v[bb] = ntloadf(state, sb + 3 * n + 2, f);
        bv[bb]  = ntloadf(state, sb + 1536 + n, f);
        xv[bb]  = ntloadf(state, sb + 2048 + n, f);
    }
    __syncthreads();

    const uint16_t* bpe = sT + bq * 520 + quad * 8;   // B-frag base (per-lane)

    // ---- ic GEMM: 4 n-tiles x 4 ks of mfma over Winsw ----
    {
        const uint16_t* api = Winsw + ((size_t)(k * 32 + 4 * w) * 4) * 512 + (size_t)lane * 8;
        floatx4 d0 = {0.f,0.f,0.f,0.f}, d1 = d0, d2 = d0, d3 = d0;
        #pragma unroll
        for (int ks = 0; ks < 4; ++ks) {
            short8 bf = *(const short8*)(bpe + ks * 32);
            short8 a0f = *(const short8*)(api + (0 * 4 + ks) * 512);
            short8 a1f = *(const short8*)(api + (1 * 4 + ks) * 512);
            short8 a2f = *(const short8*)(api + (2 * 4 + ks) * 512);
            short8 a3f = *(const short8*)(api + (3 * 4 + ks) * 512);
            d0 = __builtin_amdgcn_mfma_f32_16x16x32_bf16(a0f, bf, d0, 0, 0, 0);
            d1 = __builtin_amdgcn_mfma_f32_16x16x32_bf16(a1f, bf, d1, 0, 0, 0);
            d2 = __builtin_amdgcn_mfma_f32_16x16x32_bf16(a2f, bf, d2, 0, 0, 0);
            d3 = __builtin_amdgcn_mfma_f32_16x16x32_bf16(a3f, bf, d3, 0, 0, 0);
        }
        const int nb = w * 64 + quad * 4;
        *(floatx4*)(&synT[bq * 516 + nb +  0]) = d0;
        *(floatx4*)(&synT[bq * 516 + nb + 16]) = d1;
        *(floatx4*)(&synT[bq * 516 + nb + 32]) = d2;
        *(floatx4*)(&synT[bq * 516 + nb + 48]) = d3;
    }
    __syncthreads();
    #pragma unroll
    for (int bb = 0; bb < 16; ++bb) ic[bb] = synT[bb * 516 + n];
    __syncthreads();

    // per-lane recurrent A-frag base
    const uint16_t* ape = Wsw + (size_t)k * 32 * 8192 + (size_t)(4 * w) * 8192 + (size_t)lane * 8;

    for (int step = 0; step < UNFOLDS_; ++step) {
        // elementwise: r from (a,x); update a,b; stage s (bf16, transposed)
        #pragma unroll
        for (int bb = 0; bb < 16; ++bb) {
            float thr = thr0 + a0v[bb] + a1v[bb] + a2v[bb];
            float r = psig(xv[bb] - thr);
            float s = r * bv[bb];
            a0v[bb] = fmaf(amul0, r, a0v[bb]) * ainv0;
            a1v[bb] = fmaf(amul1, r, a1v[bb]) * ainv1;
            a2v[bb] = fmaf(amul2, r, a2v[bb]) * ainv2;
            bv[bb] = (bv[bb] + grec) / (1.f + grec + grel * r);
            sT[bb * 520 + n] = f2b(s);
        }
        __syncthreads();

        // GEMM: 4 n-tiles x 16 ks of mfma_f32_16x16x32_bf16 (Wsw streams from L2)
        floatx4 c0 = {0.f, 0.f, 0.f, 0.f}, c1 = c0, c2 = c0, c3 = c0;
        #pragma unroll 4
        for (int ks = 0; ks < 16; ++ks) {
            short8 bf = *(const short8*)(bpe + ks * 32);
            short8 af0 = *(const short8*)(ape + ks * 512);
            short8 af1 = *(const short8*)(ape + 8192 + ks * 512);
            short8 af2 = *(const short8*)(ape + 16384 + ks * 512);
            short8 af3 = *(const short8*)(ape + 24576 + ks * 512);
            c0 = __builtin_amdgcn_mfma_f32_16x16x32_bf16(af0, bf, c0, 0, 0, 0);
            c1 = __builtin_amdgcn_mfma_f32_16x16x32_bf16(af1, bf, c1, 0, 0, 0);
            c2 = __builtin_amdgcn_mfma_f32_16x16x32_bf16(af2, bf, c2, 0, 0, 0);
            c3 = __builtin_amdgcn_mfma_f32_16x16x32_bf16(af3, bf, c3, 0, 0, 0);
        }
        // C/D layout: col = lane&15 (=b), row = quad*4 + reg (+16 per n-tile)
        {
            const int nb = w * 64 + quad * 4;
            *(floatx4*)(&synT[bq * 516 + nb +  0]) = c0;
            *(floatx4*)(&synT[bq * 516 + nb + 16]) = c1;
            *(floatx4*)(&synT[bq * 516 + nb + 32]) = c2;
            *(floatx4*)(&synT[bq * 516 + nb + 48]) = c3;
        }
        __syncthreads();

        // x update (n-per-thread layout)
        #pragma unroll
        for (int bb = 0; bb < 16; ++bb) {
            float syn = synT[bb * 516 + n] + ic[bb];
            xv[bb] = fmaf(gx, syn, xv[bb]) * ivgx;
        }
    }

    // final rate_syn + epilogue (dtype-adaptive, non-temporal stores)
    const int rid = readout[k];
    if (f) {
        float* outp = (float*)out;
        float* nst = outp + (size_t)K_ * B_ * N_;
        #pragma unroll
        for (int bb = 0; bb < 16; ++bb) {
            float thr = thr0 + a0v[bb] + a1v[bb] + a2v[bb];
            float r = psig(xv[bb] - thr);
            float s = r * bv[bb];
            float o = (rid == 0) ? s : ((rid == 1) ? r : xv[bb]);
            size_t ob = (size_t)k * B_ + b0 + bb;
            __builtin_nontemporal_store(o, outp + ob * N_ + n);
            float* st = nst + ob * STATE_;
            __builtin_nontemporal_store(a0v[bb], st + 3 * n + 0);
            __builtin_nontemporal_store(a1v[bb], st + 3 * n + 1);
            __builtin_nontemporal_store(a2v[bb], st + 3 * n + 2);
            __builtin_nontemporal_store(bv[bb], st + 1536 + n);
            __builtin_nontemporal_store(xv[bb], st + 2048 + n);
        }
    } else {
        uint16_t* outp = (uint16_t*)out;
        uint16_t* nst = outp + (size_t)K_ * B_ * N_;
        #pragma unroll
        for (int bb = 0; bb < 16; ++bb) {
            float thr = thr0 + a0v[bb] + a1v[bb] + a2v[bb];
            float r = psig(xv[bb] - thr);
            float s = r * bv[bb];
            float o = (rid == 0) ? s : ((rid == 1) ? r : xv[bb]);
            size_t ob = (size_t)k * B_ + b0 + bb;
            __builtin_nontemporal_store(f2b(o), outp + ob * N_ + n);
            uint16_t* st = nst + ob * STATE_;
            __builtin_nontemporal_store(f2b(a0v[bb]), st + 3 * n + 0);
            __builtin_nontemporal_store(f2b(a1v[bb]), st + 3 * n + 1);
            __builtin_nontemporal_store(f2b(a2v[bb]), st + 3 * n + 2);
            __builtin_nontemporal_store(f2b(bv[bb]), st + 1536 + n);
            __builtin_nontemporal_store(f2b(xv[bb]), st + 2048 + n);
        }
    }
}

extern "C" void kernel_launch(void* const* d_in, const int* in_sizes, int n_in,
                              void* d_out, int out_size, void* d_ws, size_t ws_size,
                              hipStream_t stream) {
    const void* inputs = d_in[0];
    const void* state  = d_in[1];
    const void* Wraw   = d_in[2];
    const void* mask   = d_in[3];
    const void* Win    = d_in[4];
    const void* a0     = d_in[5];
    const void* ltd    = d_in[6];
    const void* ltaE   = d_in[7];
    const void* lcE    = d_in[8];
    const void* c0E    = d_in[9];
    const void* ltaI   = d_in[10];
    const void* lcI    = d_in[11];
    const void* c0I    = d_in[12];
    const void* lbrecE = d_in[13];
    const void* lbrelE = d_in[14];
    const void* lbrecI = d_in[15];
    const void* lbrelI = d_in[16];
    const int* readout = (const int*)d_in[17];

    // workspace: flag 256 B | P 180224 B | Wsw 4 MiB | Winsw 1 MiB (~5.4 MiB)
    char* ws = (char*)d_ws;
    int* flag       = (int*)ws;
    float* P        = (float*)(ws + 256);
    uint16_t* Wsw   = (uint16_t*)(ws + 256 + 180224);
    uint16_t* Winsw = (uint16_t*)(ws + 256 + 180224 + 4194304);

    srnn_detect_kernel<<<dim3(1), dim3(256), 0, stream>>>((const uint16_t*)Wraw, flag);
    srnn_params_kernel<<<dim3(16), dim3(256), 0, stream>>>(
        a0, ltd, ltaE, lcE, c0E, ltaI, lcI, c0I, lbrecE, lbrelE, lbrecI, lbrelI, flag, P);
    srnn_wsw_kernel<<<dim3(32, 8), dim3(256), 0, stream>>>(Wraw, mask, flag, Wsw);
    srnn_winsw_kernel<<<dim3(32, 8), dim3(256), 0, stream>>>(Win, flag, Winsw);
    srnn_main_kernel<<<dim3(512), dim3(512), 0, stream>>>(
        state, inputs, Wsw, Winsw, P, readout, flag, d_out);
}